// Round 6
// baseline (212.820 us; speedup 1.0000x reference)
//
#include <hip/hip_runtime.h>
#include <hip/hip_bf16.h>
#include <hip/hip_cooperative_groups.h>

namespace cg = cooperative_groups;

#define BB 4096   // batch
#define DD 64     // event dim
#define HH 512    // hidden

typedef short short8 __attribute__((ext_vector_type(8)));   // 8 bf16
typedef float f32x4  __attribute__((ext_vector_type(4)));
typedef __hip_bfloat16 bf16;

// async global->LDS, 16B per lane; LDS dest is wave-uniform base + lane*16
#define GLOAD_LDS16(gp, lp)                                                \
  __builtin_amdgcn_global_load_lds(                                        \
      (const __attribute__((address_space(1))) void*)(gp),                 \
      (__attribute__((address_space(3))) void*)(lp), 16, 0, 0)

// branchless fast tanh: 1 - 2/(1+e^{2x}); exact limits at +-inf
__device__ __forceinline__ float tanh_fast(float x) {
    float e = __expf(2.0f * x);
    return 1.0f - __fdividef(2.0f, 1.0f + e);
}

// ---------------------------------------------------------------------------
// prep work, one virtual block (256 threads) per vb:
//  [0,256)   W2t[n][k] = bf16(W2[k][n])   (32x32 LDS-tiled transpose)
//  [256,288) W1t[j][d] = bf16(W1[d][j])
//  [288,320) W3t[e][k] = bf16(W3[k][e])
//  [320,384) Pt[k][j]  = bf16(W2[j][k] * sum_d W1[d][j]*W3[k][d])
//  [384,640) z f32 -> bf16
//  640       b1eff[j]  = b1[j] + t*W1[64][j]
//  [641,645) zero out_tr
// ---------------------------------------------------------------------------
__device__ void prep_work(
    int vb, int tid, float (*tile)[33],
    const float* __restrict__ z, const float* __restrict__ t,
    const float* __restrict__ W1, const float* __restrict__ b1,
    const float* __restrict__ W2, const float* __restrict__ W3,
    bf16* __restrict__ z_b, bf16* __restrict__ W1t, bf16* __restrict__ W2t,
    bf16* __restrict__ W3t, bf16* __restrict__ Pt, float* __restrict__ b1eff,
    float* __restrict__ out_tr)
{
    const int tx = tid & 31, ty = tid >> 5;   // 32 x 8

    if (vb < 256) {
        int r0 = (vb >> 4) * 32, c0 = (vb & 15) * 32;
#pragma unroll
        for (int i = 0; i < 32; i += 8)
            tile[ty + i][tx] = W2[(size_t)(r0 + ty + i) * HH + c0 + tx];
        __syncthreads();
#pragma unroll
        for (int i = 0; i < 32; i += 8)
            W2t[(size_t)(c0 + ty + i) * HH + r0 + tx] = __float2bfloat16(tile[tx][ty + i]);
    } else if (vb < 288) {
        int b = vb - 256;
        int r0 = (b >> 4) * 32, c0 = (b & 15) * 32;   // d-rows, j-cols
#pragma unroll
        for (int i = 0; i < 32; i += 8)
            tile[ty + i][tx] = W1[(size_t)(r0 + ty + i) * HH + c0 + tx];
        __syncthreads();
#pragma unroll
        for (int i = 0; i < 32; i += 8)
            W1t[(size_t)(c0 + ty + i) * DD + r0 + tx] = __float2bfloat16(tile[tx][ty + i]);
    } else if (vb < 320) {
        int b = vb - 288;
        int r0 = (b >> 1) * 32, c0 = (b & 1) * 32;    // k-rows, e-cols
#pragma unroll
        for (int i = 0; i < 32; i += 8)
            tile[ty + i][tx] = W3[(size_t)(r0 + ty + i) * DD + c0 + tx];
        __syncthreads();
#pragma unroll
        for (int i = 0; i < 32; i += 8)
            W3t[(size_t)(c0 + ty + i) * HH + r0 + tx] = __float2bfloat16(tile[tx][ty + i]);
    } else if (vb < 384) {
        int b = vb - 320;
        int k0 = b * 8;
        int j0 = tid * 2;
        float acc0[8] = {}, acc1[8] = {};
        for (int d = 0; d < 64; ++d) {
            float w1a = W1[(size_t)d * HH + j0];
            float w1b = W1[(size_t)d * HH + j0 + 1];
#pragma unroll
            for (int kk = 0; kk < 8; ++kk) {
                float w3 = W3[(size_t)(k0 + kk) * DD + d];
                acc0[kk] += w1a * w3;
                acc1[kk] += w1b * w3;
            }
        }
#pragma unroll
        for (int kk = 0; kk < 8; ++kk) {
            int k = k0 + kk;
            Pt[(size_t)k * HH + j0]     = __float2bfloat16(acc0[kk] * W2[(size_t)j0 * HH + k]);
            Pt[(size_t)k * HH + j0 + 1] = __float2bfloat16(acc1[kk] * W2[(size_t)(j0 + 1) * HH + k]);
        }
    } else if (vb < 640) {
        int i = ((vb - 384) * 256 + tid) * 4;
        float4 v = *(const float4*)(z + i);
        z_b[i + 0] = __float2bfloat16(v.x);
        z_b[i + 1] = __float2bfloat16(v.y);
        z_b[i + 2] = __float2bfloat16(v.z);
        z_b[i + 3] = __float2bfloat16(v.w);
    } else if (vb == 640) {
        float tv = t[0];
        b1eff[tid]       = b1[tid]       + tv * W1[(size_t)64 * HH + tid];
        b1eff[tid + 256] = b1[tid + 256] + tv * W1[(size_t)64 * HH + tid + 256];
    } else {
        int i = ((vb - 641) * 256 + tid) * 4;
        *(float4*)(out_tr + i) = make_float4(0.f, 0.f, 0.f, 0.f);
    }
}

// ---------------------------------------------------------------------------
// GEMM body (proven round-4 structure): C[M,N] = A[M,K] * Bt[N,K]^T.
// 64x64 block tile, BK=64, 4-deep LDS ring (each buffer 4096 ELEMENTS =
// 8192 BYTES; As/Bs each need 32768 BYTES), stage 2 ahead via
// global_load_lds(16B), ONE raw s_barrier per K-step with counted vmcnt.
// XOR chunk-swizzle both-sides (rule 21). 4 waves 2x2, wave=32x32.
// vmcnt(0) drain at entry (prior phase's stores share the counter).
//  EPI 0: h = tanh(acc+bias[col]) -> outH; 1-h^2 -> outA
//  EPI 1: outF = acc + bias[col]
//  EPI 2: trace: p = sum_col acc*bs; shfl-reduce; atomicAdd(outTr+row,-p)
// ---------------------------------------------------------------------------
template <int EPI, int K, int N>
__device__ void gemm_body(
    const bf16* __restrict__ A, const bf16* __restrict__ Bt,
    const float* __restrict__ bias,
    bf16* __restrict__ outH, bf16* __restrict__ outA,
    const bf16* __restrict__ bs, float* __restrict__ outF,
    float* __restrict__ outTr,
    int bm, int bn, bf16* As, bf16* Bs)
{
    const int tid  = threadIdx.x;
    const int wid  = tid >> 6;
    const int lane = tid & 63;
    const int r    = lane & 15;
    const int kq   = lane >> 4;
    const int wm   = (wid >> 1) * 32;
    const int wn   = (wid & 1) * 32;

    // LDS read offsets (bf16 elements), swizzled chunk addressing
    int offA[2][2], offB[2][2];
#pragma unroll
    for (int mi = 0; mi < 2; ++mi) {
        int row = wm + mi * 16 + r;
#pragma unroll
        for (int ks = 0; ks < 2; ++ks)
            offA[mi][ks] = row * 64 + ((((ks * 4 + kq) ^ (row & 7))) << 3);
    }
#pragma unroll
    for (int ni = 0; ni < 2; ++ni) {
        int row = wn + ni * 16 + r;
#pragma unroll
        for (int ks = 0; ks < 2; ++ks)
            offB[ni][ks] = row * 64 + ((((ks * 4 + kq) ^ (row & 7))) << 3);
    }

    // staging source pattern: i = rnd*256+tid -> row=i>>3, chunk=(i&7)^(row&7)
    const int i0   = tid;
    const int i1   = 256 + tid;
    const int row0 = i0 >> 3, row1 = i1 >> 3;
    const int c0   = ((i0 & 7) ^ (row0 & 7)) << 3;
    const int c1   = ((i1 & 7) ^ (row1 & 7)) << 3;
    const bf16* a_src0 = A  + (size_t)(bm + row0) * K + c0;
    const bf16* a_src1 = A  + (size_t)(bm + row1) * K + c1;
    const bf16* b_src0 = Bt + (size_t)(bn + row0) * K + c0;
    const bf16* b_src1 = Bt + (size_t)(bn + row1) * K + c1;

    auto stage = [&](int t) {        // t compile-time after full unroll
        const int b  = t & 3;
        const int k0 = t * 64;
        GLOAD_LDS16(a_src0 + k0, As + b * 4096 + i0 * 8);
        GLOAD_LDS16(b_src0 + k0, Bs + b * 4096 + i0 * 8);
        GLOAD_LDS16(a_src1 + k0, As + b * 4096 + i1 * 8);
        GLOAD_LDS16(b_src1 + k0, Bs + b * 4096 + i1 * 8);
    };

    f32x4 acc[2][2] = {};
    constexpr int NS = K / 64;

    // entry drain: prior phase's stores/atomics share this wave's vmcnt
    asm volatile("s_waitcnt vmcnt(0)" ::: "memory");

    stage(0);
    if (NS > 1) stage(1);

#pragma unroll
    for (int t = 0; t < NS; ++t) {
        if (t + 2 < NS) stage(t + 2);
        if (t + 2 < NS)      asm volatile("s_waitcnt vmcnt(8)" ::: "memory");
        else if (t + 1 < NS) asm volatile("s_waitcnt vmcnt(4)" ::: "memory");
        else                 asm volatile("s_waitcnt vmcnt(0)" ::: "memory");
        __builtin_amdgcn_s_barrier();
        asm volatile("" ::: "memory");   // pin LDS reads below the barrier

        const bf16* a_base = As + (t & 3) * 4096;
        const bf16* b_base = Bs + (t & 3) * 4096;
        short8 af[2][2], bfr[2][2];
#pragma unroll
        for (int mi = 0; mi < 2; ++mi)
#pragma unroll
            for (int ks = 0; ks < 2; ++ks)
                af[mi][ks] = *(const short8*)(a_base + offA[mi][ks]);
#pragma unroll
        for (int ni = 0; ni < 2; ++ni)
#pragma unroll
            for (int ks = 0; ks < 2; ++ks)
                bfr[ni][ks] = *(const short8*)(b_base + offB[ni][ks]);
#pragma unroll
        for (int ks = 0; ks < 2; ++ks)
#pragma unroll
            for (int mi = 0; mi < 2; ++mi)
#pragma unroll
                for (int ni = 0; ni < 2; ++ni)
                    acc[mi][ni] = __builtin_amdgcn_mfma_f32_16x16x32_bf16(
                        af[mi][ks], bfr[ni][ks], acc[mi][ni], 0, 0, 0);
    }

    // epilogue
#pragma unroll
    for (int mi = 0; mi < 2; ++mi) {
        if (EPI == 2) {
#pragma unroll
            for (int v = 0; v < 4; ++v) {
                int row = bm + wm + mi * 16 + kq * 4 + v;
                float p = 0.f;
#pragma unroll
                for (int ni = 0; ni < 2; ++ni) {
                    int col = bn + wn + ni * 16 + r;
                    float bsv = __bfloat162float(bs[(size_t)row * N + col]);
                    p += acc[mi][ni][v] * bsv;
                }
                p += __shfl_xor(p, 1);
                p += __shfl_xor(p, 2);
                p += __shfl_xor(p, 4);
                p += __shfl_xor(p, 8);
                if (r == 0) atomicAdd(outTr + row, -p);
            }
        } else {
#pragma unroll
            for (int ni = 0; ni < 2; ++ni) {
#pragma unroll
                for (int v = 0; v < 4; ++v) {
                    int row = bm + wm + mi * 16 + kq * 4 + v;
                    int col = bn + wn + ni * 16 + r;
                    float val = acc[mi][ni][v] + bias[col];
                    size_t o = (size_t)row * N + col;
                    if (EPI == 0) {
                        float h = tanh_fast(val);
                        outH[o] = __float2bfloat16(h);
                        outA[o] = __float2bfloat16(fmaf(-h, h, 1.0f));
                    } else {
                        outF[o] = val;
                    }
                }
            }
        }
    }
}

// ---------------------------------------------------------------------------
// cooperative mega kernel: 512 blocks x 256 threads, 4 phases + 3 grid syncs
//   phase 0: prep (vblock loop) ; phase 1: L1 ; phase 2: L2 ;
//   phase 3: E (all blocks) + L3 (bn==7 blocks, second gemm_body)
// LDS: As = 32768 BYTES (4 bufs x 4096 bf16), Bs = 32768 BYTES -> 64 KiB
// total, 2 blocks/CU, 512 blocks == 2 x 256 CUs co-resident.
// ---------------------------------------------------------------------------
__global__ __launch_bounds__(256) void mega_coop(
    const float* __restrict__ z, const float* __restrict__ t,
    const float* __restrict__ W1, const float* __restrict__ b1,
    const float* __restrict__ W2, const float* __restrict__ b2,
    const float* __restrict__ W3, const float* __restrict__ b3,
    bf16* __restrict__ z_b, bf16* __restrict__ W1t, bf16* __restrict__ W2t,
    bf16* __restrict__ W3t, bf16* __restrict__ Pt, float* __restrict__ b1eff,
    bf16* __restrict__ h1b, bf16* __restrict__ ab, bf16* __restrict__ h2b,
    bf16* __restrict__ bsb, float* __restrict__ outV, float* __restrict__ outTr)
{
    __shared__ alignas(16) char smem[65536];
    bf16* As = (bf16*)smem;               // 4*4096 elems = 32768 bytes
    bf16* Bs = (bf16*)(smem + 32768);     // 4*4096 elems = 32768 bytes
    float (*tile)[33] = (float (*)[33])smem;

    const int tid = threadIdx.x;
    const int bid = blockIdx.x;
    const int bm  = (bid & 63) * 64;
    const int bn  = (bid >> 6);
    cg::grid_group grid = cg::this_grid();

    // ---- phase 0: prep ----
    for (int vb = bid; vb < 645; vb += 512) {
        prep_work(vb, tid, tile, z, t, W1, b1, W2, W3,
                  z_b, W1t, W2t, W3t, Pt, b1eff, outTr);
        __syncthreads();
    }
    grid.sync();

    // ---- phase 1: h1 = tanh(z@W1 + b1eff); a = 1-h1^2 ----
    gemm_body<0, 64, 512>(z_b, W1t, b1eff, h1b, ab, nullptr, nullptr, nullptr,
                          bm, bn * 64, As, Bs);
    grid.sync();

    // ---- phase 2: h2 = tanh(h1@W2 + b2); bsq = 1-h2^2 ----
    gemm_body<0, 512, 512>(h1b, W2t, b2, h2b, bsb, nullptr, nullptr, nullptr,
                           bm, bn * 64, As, Bs);
    grid.sync();

    // ---- phase 3: E (trace) on all blocks; L3 (v) on bn==7 blocks ----
    gemm_body<2, 512, 512>(ab, Pt, nullptr, nullptr, nullptr, bsb, nullptr,
                           outTr, bm, bn * 64, As, Bs);
    if (bn == 7)
        gemm_body<1, 512, 64>(h2b, W3t, b3, nullptr, nullptr, nullptr, outV,
                              nullptr, bm, 0, As, Bs);
}

extern "C" void kernel_launch(void* const* d_in, const int* in_sizes, int n_in,
                              void* d_out, int out_size, void* d_ws, size_t ws_size,
                              hipStream_t stream)
{
    const float* z  = (const float*)d_in[0];
    const float* t  = (const float*)d_in[2];
    const float* W1 = (const float*)d_in[3];
    const float* b1 = (const float*)d_in[4];
    const float* W2 = (const float*)d_in[5];
    const float* b2 = (const float*)d_in[6];
    const float* W3 = (const float*)d_in[7];
    const float* b3 = (const float*)d_in[8];
    float* out = (float*)d_out;                 // v [4096*64] then dlogp [4096]
    float* out_tr = out + (size_t)BB * DD;

    char* w = (char*)d_ws;
    auto alloc = [&](size_t bytes) {
        char* p = w;
        w += (bytes + 255) & ~(size_t)255;
        return p;
    };
    bf16* z_b   = (bf16*)alloc((size_t)BB * DD * 2);
    bf16* W1t   = (bf16*)alloc((size_t)HH * DD * 2);
    bf16* W2t   = (bf16*)alloc((size_t)HH * HH * 2);
    bf16* W3t   = (bf16*)alloc((size_t)DD * HH * 2);
    bf16* Pt    = (bf16*)alloc((size_t)HH * HH * 2);
    float* b1eff = (float*)alloc((size_t)HH * 4);
    bf16* h1b   = (bf16*)alloc((size_t)BB * HH * 2);
    bf16* ab    = (bf16*)alloc((size_t)BB * HH * 2);
    bf16* h2b   = (bf16*)alloc((size_t)BB * HH * 2);
    bf16* bsb   = (bf16*)alloc((size_t)BB * HH * 2);

    void* args[] = {
        (void*)&z, (void*)&t, (void*)&W1, (void*)&b1, (void*)&W2, (void*)&b2,
        (void*)&W3, (void*)&b3, (void*)&z_b, (void*)&W1t, (void*)&W2t,
        (void*)&W3t, (void*)&Pt, (void*)&b1eff, (void*)&h1b, (void*)&ab,
        (void*)&h2b, (void*)&bsb, (void*)&out, (void*)&out_tr
    };
    hipLaunchCooperativeKernel((const void*)mega_coop, dim3(512), dim3(256),
                               args, 0, stream);
}

// Round 7
// 48.552 us; speedup vs baseline: 4.3833x; 4.3833x over previous
//
#include <hip/hip_runtime.h>
#include <hip/hip_bf16.h>

#define BB 4096   // batch
#define DD 64     // event dim
#define HH 512    // hidden

typedef short short8 __attribute__((ext_vector_type(8)));   // 8 bf16
typedef float f32x4  __attribute__((ext_vector_type(4)));
typedef __hip_bfloat16 bf16;

// branchless fast tanh: 1 - 2/(1+e^{2x}); exact limits at +-inf
__device__ __forceinline__ float tanh_fast(float x) {
    float e = __expf(2.0f * x);
    return 1.0f - __fdividef(2.0f, 1.0f + e);
}

// swizzled LDS bf16 store: 8-elem chunk index XOR'd with row&7 (write side)
__device__ __forceinline__ void st_swz(bf16* base, int row, int col, int rs, float v) {
    base[row * rs + ((((col >> 3) ^ (row & 7))) << 3) + (col & 7)] = __float2bfloat16(v);
}

// ---------------------------------------------------------------------------
// prep kernel (385 blocks x 256): weight transposes to bf16 + P + b1eff
//  [0,256)   W2t[n][k] = bf16(W2[k][n])   (32x32 LDS-tiled transpose)
//  [256,288) W1t[j][d] = bf16(W1[d][j])  (d<64)
//  [288,320) W3t[e][k] = bf16(W3[k][e])
//  [320,384) Pt[k][j]  = bf16(W2[j][k] * sum_d W1[d][j]*W3[k][d])
//  384       b1eff[j]  = b1[j] + t*W1[64][j]
// ---------------------------------------------------------------------------
__global__ __launch_bounds__(256) void prep_kernel(
    const float* __restrict__ t, const float* __restrict__ W1,
    const float* __restrict__ b1, const float* __restrict__ W2,
    const float* __restrict__ W3,
    bf16* __restrict__ W1t, bf16* __restrict__ W2t, bf16* __restrict__ W3t,
    bf16* __restrict__ Pt, float* __restrict__ b1eff)
{
    __shared__ float tile[32][33];
    const int tid = threadIdx.x;
    const int bx  = blockIdx.x;
    const int tx = tid & 31, ty = tid >> 5;   // 32 x 8

    if (bx < 256) {
        int r0 = (bx >> 4) * 32, c0 = (bx & 15) * 32;
#pragma unroll
        for (int i = 0; i < 32; i += 8)
            tile[ty + i][tx] = W2[(size_t)(r0 + ty + i) * HH + c0 + tx];
        __syncthreads();
#pragma unroll
        for (int i = 0; i < 32; i += 8)
            W2t[(size_t)(c0 + ty + i) * HH + r0 + tx] = __float2bfloat16(tile[tx][ty + i]);
    } else if (bx < 288) {
        int b = bx - 256;
        int r0 = (b >> 4) * 32, c0 = (b & 15) * 32;   // d-rows, j-cols
#pragma unroll
        for (int i = 0; i < 32; i += 8)
            tile[ty + i][tx] = W1[(size_t)(r0 + ty + i) * HH + c0 + tx];
        __syncthreads();
#pragma unroll
        for (int i = 0; i < 32; i += 8)
            W1t[(size_t)(c0 + ty + i) * DD + r0 + tx] = __float2bfloat16(tile[tx][ty + i]);
    } else if (bx < 320) {
        int b = bx - 288;
        int r0 = (b >> 1) * 32, c0 = (b & 1) * 32;    // k-rows, e-cols
#pragma unroll
        for (int i = 0; i < 32; i += 8)
            tile[ty + i][tx] = W3[(size_t)(r0 + ty + i) * DD + c0 + tx];
        __syncthreads();
#pragma unroll
        for (int i = 0; i < 32; i += 8)
            W3t[(size_t)(c0 + ty + i) * HH + r0 + tx] = __float2bfloat16(tile[tx][ty + i]);
    } else if (bx < 384) {
        int b = bx - 320;
        int k0 = b * 8;
        int j0 = tid * 2;
        float acc0[8] = {}, acc1[8] = {};
        for (int d = 0; d < 64; ++d) {
            float w1a = W1[(size_t)d * HH + j0];
            float w1b = W1[(size_t)d * HH + j0 + 1];
#pragma unroll
            for (int kk = 0; kk < 8; ++kk) {
                float w3 = W3[(size_t)(k0 + kk) * DD + d];
                acc0[kk] += w1a * w3;
                acc1[kk] += w1b * w3;
            }
        }
#pragma unroll
        for (int kk = 0; kk < 8; ++kk) {
            int k = k0 + kk;
            Pt[(size_t)k * HH + j0]     = __float2bfloat16(acc0[kk] * W2[(size_t)j0 * HH + k]);
            Pt[(size_t)k * HH + j0 + 1] = __float2bfloat16(acc1[kk] * W2[(size_t)(j0 + 1) * HH + k]);
        }
    } else {
        float tv = t[0];
        b1eff[tid]       = b1[tid]       + tv * W1[(size_t)64 * HH + tid];
        b1eff[tid + 256] = b1[tid + 256] + tv * W1[(size_t)64 * HH + tid + 256];
    }
}

// ---------------------------------------------------------------------------
// mm_phase: one wave computes a [16 x 64] output strip over K = NS*32.
// A: swizzled LDS tile (row stride RS elems); lane (r,kq) reads chunk
//    (ckBase + s*4 + kq) ^ (row&7) of its row via ds_read_b128.
// B: direct-from-global b128 per lane (Bt row-major [col][K]), static
//    1-step double buffer (all indices compile-time -> registers).
// ---------------------------------------------------------------------------
template <int NS, int RS>
__device__ __forceinline__ void mm_phase(
    const bf16* __restrict__ aT, int arow, int kq, int ckBase,
    const bf16* const* pB, f32x4* acc)
{
    const int rx = arow & 7;
    const bf16* pa = aT + arow * RS;
    short8 a[2];
    short8 b[2][4];
    a[0] = *(const short8*)(pa + (((ckBase + kq) ^ rx) << 3));
#pragma unroll
    for (int ni = 0; ni < 4; ++ni)
        b[0][ni] = *(const short8*)(pB[ni]);
#pragma unroll
    for (int s = 0; s < NS; ++s) {
        if (s + 1 < NS) {
            a[(s + 1) & 1] = *(const short8*)(pa + (((ckBase + (s + 1) * 4 + kq) ^ rx) << 3));
#pragma unroll
            for (int ni = 0; ni < 4; ++ni)
                b[(s + 1) & 1][ni] = *(const short8*)(pB[ni] + (s + 1) * 32);
        }
#pragma unroll
        for (int ni = 0; ni < 4; ++ni)
            acc[ni] = __builtin_amdgcn_mfma_f32_16x16x32_bf16(
                a[s & 1], b[s & 1][ni], acc[ni], 0, 0, 0);
    }
}

// ---------------------------------------------------------------------------
// fused_rows: 256 blocks x 512 threads (8 waves). Block = 16 batch rows
// through L1 -> L2 -> E -> L3; h1/a/h2 in swizzled LDS; weights streamed
// from L2 per wave (wave w owns cols [64w,64w+64) in N=512 phases).
// Trace: in-wave shfl reduce + LDS partials (no atomics).
// L3: 8-way split-K -> LDS partials -> block reduce (no atomics).
// ---------------------------------------------------------------------------
__global__ __launch_bounds__(512) void fused_rows(
    const float* __restrict__ z, const bf16* __restrict__ W1t,
    const bf16* __restrict__ W2t, const bf16* __restrict__ W3t,
    const bf16* __restrict__ Pt, const float* __restrict__ b1eff,
    const float* __restrict__ b2, const float* __restrict__ b3,
    float* __restrict__ outV, float* __restrict__ outTr)
{
    __shared__ alignas(16) char smem[51712];
    bf16* zt = (bf16*)smem;                   // [16][64]  swizzled
    bf16* h1 = (bf16*)(smem + 2048);          // [16][512] swizzled
    bf16* at = (bf16*)(smem + 18432);         // [16][512] swizzled
    bf16* h2 = (bf16*)(smem + 34816);         // [16][512] swizzled
    float* trp = (float*)(smem + 51200);      // [8][16]
    float* vp  = (float*)(smem + 2048);       // [8][16][64] overlays h1+at

    const int tid  = threadIdx.x;
    const int wid  = tid >> 6;
    const int lane = tid & 63;
    const int r    = lane & 15;
    const int kq   = lane >> 4;
    const int cb   = wid * 64;
    const int bm   = blockIdx.x * 16;

    // ---- stage z: 16x64 f32 -> bf16 swizzled LDS ----
    {
        int row = tid >> 5;
        int col = (tid * 2) & 63;
        float2 v = *(const float2*)(z + (size_t)(bm + row) * DD + col);
        st_swz(zt, row, col,     64, v.x);
        st_swz(zt, row, col + 1, 64, v.y);
    }
    __syncthreads();

    // ---- L1: h1 = tanh(z @ W1 + b1eff); a = 1 - h1^2 ----
    {
        const bf16* pB[4];
#pragma unroll
        for (int ni = 0; ni < 4; ++ni)
            pB[ni] = W1t + (size_t)(cb + ni * 16 + r) * DD + kq * 8;
        f32x4 acc[4] = {};
        mm_phase<2, 64>(zt, r, kq, 0, pB, acc);
#pragma unroll
        for (int ni = 0; ni < 4; ++ni) {
            int col = cb + ni * 16 + r;
            float bias = b1eff[col];
#pragma unroll
            for (int v = 0; v < 4; ++v) {
                int row = kq * 4 + v;
                float h = tanh_fast(acc[ni][v] + bias);
                st_swz(h1, row, col, 512, h);
                st_swz(at, row, col, 512, fmaf(-h, h, 1.0f));
            }
        }
    }
    __syncthreads();

    // ---- L2: h2 = tanh(h1 @ W2 + b2); bsq kept in registers ----
    f32x4 bsq[4];
    {
        const bf16* pB[4];
#pragma unroll
        for (int ni = 0; ni < 4; ++ni)
            pB[ni] = W2t + (size_t)(cb + ni * 16 + r) * HH + kq * 8;
        f32x4 acc[4] = {};
        mm_phase<16, 512>(h1, r, kq, 0, pB, acc);
#pragma unroll
        for (int ni = 0; ni < 4; ++ni) {
            int col = cb + ni * 16 + r;
            float bias = b2[col];
#pragma unroll
            for (int v = 0; v < 4; ++v) {
                int row = kq * 4 + v;
                float h = tanh_fast(acc[ni][v] + bias);
                st_swz(h2, row, col, 512, h);
                bsq[ni][v] = fmaf(-h, h, 1.0f);
            }
        }
    }
    __syncthreads();

    // ---- E: V = a @ P; trace partial = sum_col V*bsq ----
    {
        const bf16* pB[4];
#pragma unroll
        for (int ni = 0; ni < 4; ++ni)
            pB[ni] = Pt + (size_t)(cb + ni * 16 + r) * HH + kq * 8;
        f32x4 acc[4] = {};
        mm_phase<16, 512>(at, r, kq, 0, pB, acc);
#pragma unroll
        for (int v = 0; v < 4; ++v) {
            float p = 0.f;
#pragma unroll
            for (int ni = 0; ni < 4; ++ni)
                p += acc[ni][v] * bsq[ni][v];
            p += __shfl_xor(p, 1);
            p += __shfl_xor(p, 2);
            p += __shfl_xor(p, 4);
            p += __shfl_xor(p, 8);
            if (r == 0) trp[wid * 16 + kq * 4 + v] = p;
        }
    }
    __syncthreads();   // all waves done with at/h1 -> vp overlay safe

    // ---- L3: v = h2 @ W3 + b3; 8-way split-K (wave w: k in [64w,64w+64)) ----
    {
        const bf16* pB[4];
#pragma unroll
        for (int ni = 0; ni < 4; ++ni)
            pB[ni] = W3t + (size_t)(ni * 16 + r) * HH + wid * 64 + kq * 8;
        f32x4 acc[4] = {};
        mm_phase<2, 512>(h2, r, kq, wid * 8, pB, acc);
#pragma unroll
        for (int ni = 0; ni < 4; ++ni)
#pragma unroll
            for (int v = 0; v < 4; ++v) {
                int row = kq * 4 + v, col = ni * 16 + r;
                vp[wid * 1024 + row * 64 + col] = acc[ni][v];
            }
    }
    __syncthreads();

    // ---- reduce: v outputs (+bias) and trace ----
#pragma unroll
    for (int i0 = 0; i0 < 1024; i0 += 512) {
        int i = i0 + tid;
        int row = i >> 6, col = i & 63;
        float s = 0.f;
#pragma unroll
        for (int w = 0; w < 8; ++w) s += vp[w * 1024 + i];
        outV[(size_t)(bm + row) * DD + col] = s + b3[col];
    }
    if (tid < 16) {
        float s = 0.f;
#pragma unroll
        for (int w = 0; w < 8; ++w) s += trp[w * 16 + tid];
        outTr[bm + tid] = -s;
    }
}

extern "C" void kernel_launch(void* const* d_in, const int* in_sizes, int n_in,
                              void* d_out, int out_size, void* d_ws, size_t ws_size,
                              hipStream_t stream)
{
    const float* z  = (const float*)d_in[0];
    const float* t  = (const float*)d_in[2];
    const float* W1 = (const float*)d_in[3];
    const float* b1 = (const float*)d_in[4];
    const float* W2 = (const float*)d_in[5];
    const float* b2 = (const float*)d_in[6];
    const float* W3 = (const float*)d_in[7];
    const float* b3 = (const float*)d_in[8];
    float* out = (float*)d_out;                 // v [4096*64] then dlogp [4096]
    float* out_tr = out + (size_t)BB * DD;

    char* w = (char*)d_ws;
    auto alloc = [&](size_t bytes) {
        char* p = w;
        w += (bytes + 255) & ~(size_t)255;
        return p;
    };
    bf16* W1t   = (bf16*)alloc((size_t)HH * DD * 2);
    bf16* W2t   = (bf16*)alloc((size_t)HH * HH * 2);
    bf16* W3t   = (bf16*)alloc((size_t)DD * HH * 2);
    bf16* Pt    = (bf16*)alloc((size_t)HH * HH * 2);
    float* b1eff = (float*)alloc((size_t)HH * 4);

    prep_kernel<<<385, 256, 0, stream>>>(t, W1, b1, W2, W3,
                                         W1t, W2t, W3t, Pt, b1eff);
    fused_rows<<<BB / 16, 512, 0, stream>>>(z, W1t, W2t, W3t, Pt,
                                            b1eff, b2, b3, out, out_tr);
}

// Round 8
// 44.615 us; speedup vs baseline: 4.7702x; 1.0882x over previous
//
#include <hip/hip_runtime.h>
#include <hip/hip_bf16.h>

#define BB 4096   // batch
#define DD 64     // event dim
#define HH 512    // hidden

typedef short short8 __attribute__((ext_vector_type(8)));   // 8 bf16
typedef float f32x4  __attribute__((ext_vector_type(4)));
typedef __hip_bfloat16 bf16;

// branchless fast tanh: 1 - 2/(1+e^{2x}); exact limits at +-inf
__device__ __forceinline__ float tanh_fast(float x) {
    float e = __expf(2.0f * x);
    return 1.0f - __fdividef(2.0f, 1.0f + e);
}

// swizzled LDS bf16 store: 8-elem chunk index XOR'd with row&7 (write side)
__device__ __forceinline__ void st_swz(bf16* base, int row, int col, int rs, float v) {
    base[row * rs + ((((col >> 3) ^ (row & 7))) << 3) + (col & 7)] = __float2bfloat16(v);
}

// ===========================================================================
// Packed weight layout ("fragment tiles"): for a GEMM B-operand with
// out-cols N and reduce-dim K, tile (kt, nt) covers cols [nt*16,+16) x
// k [kt*32,+32). Tile idx = kt*(N/16) + nt. Within a tile, lane l
// (kq=l>>4, r=l&15) owns 8 bf16: B[col=nt*16+r][k=kt*32+kq*8+j], j=0..7,
// stored contiguously at  pack + (tile*64 + l)*8.  A wave-step load of a
// tile is then ONE coalesced 1-KB global_load_dwordx4 per 4-tile group.
// ===========================================================================

// ---------------------------------------------------------------------------
// prep kernel: 289 blocks x 256.
//  [0,160)  : pack W1p (64 tiles), W2p (512), W3p (64)  (4 tiles/block)
//  [160,288): compute + pack Pp (512 tiles): P[j][k] = W2[j][k]*sum_d W1[d][j]W3[k][d]
//  288      : b1eff[j] = b1[j] + t*W1[64][j]
// ---------------------------------------------------------------------------
__global__ __launch_bounds__(256) void prep_kernel(
    const float* __restrict__ t, const float* __restrict__ W1,
    const float* __restrict__ b1, const float* __restrict__ W2,
    const float* __restrict__ W3,
    bf16* __restrict__ W1p, bf16* __restrict__ W2p, bf16* __restrict__ W3p,
    bf16* __restrict__ Pp, float* __restrict__ b1eff)
{
    const int tid  = threadIdx.x;
    const int bx   = blockIdx.x;
    const int lane = tid & 63;
    const int r    = lane & 15;
    const int kq   = lane >> 4;

    if (bx < 160) {
        int T = bx * 4 + (tid >> 6);
        const float* src;
        bf16* dst;
        int stride;
        if (T < 64) {            // W1p: KT=2, NT=32; tile T = kt*32+nt
            int kt = T >> 5, nt = T & 31;
            src = W1 + (size_t)(kt * 32 + kq * 8) * HH + nt * 16 + r;
            stride = HH;
            dst = W1p + ((size_t)T * 64 + lane) * 8;
        } else if (T < 576) {    // W2p: KT=16, NT=32
            int tt = T - 64;
            int kt = tt >> 5, nt = tt & 31;
            src = W2 + (size_t)(kt * 32 + kq * 8) * HH + nt * 16 + r;
            stride = HH;
            dst = W2p + ((size_t)tt * 64 + lane) * 8;
        } else {                 // W3p: KT=16, NT=4
            int tt = T - 576;
            int kt = tt >> 2, nt = tt & 3;
            src = W3 + (size_t)(kt * 32 + kq * 8) * DD + nt * 16 + r;
            stride = DD;
            dst = W3p + ((size_t)tt * 64 + lane) * 8;
        }
        short8 v;
#pragma unroll
        for (int j = 0; j < 8; ++j)
            v[j] = (short)__bfloat16_as_ushort(__float2bfloat16(src[(size_t)j * stride]));
        *(short8*)dst = v;
    } else if (bx < 288) {
        // Pp tile tt: out-col = orig k (nt), reduce = j (kt)
        int tt = (bx - 160) * 4 + (tid >> 6);
        int ktj = tt >> 5, ntk = tt & 31;
        int k  = ntk * 16 + r;
        int j0 = ktj * 32 + kq * 8;
        float acc[8] = {};
        const float* w3row = W3 + (size_t)k * DD;
        for (int d = 0; d < DD; ++d) {
            float w3 = w3row[d];
            const float4* w1p4 = (const float4*)(W1 + (size_t)d * HH + j0);
            float4 x = w1p4[0], y = w1p4[1];
            acc[0] += x.x * w3; acc[1] += x.y * w3;
            acc[2] += x.z * w3; acc[3] += x.w * w3;
            acc[4] += y.x * w3; acc[5] += y.y * w3;
            acc[6] += y.z * w3; acc[7] += y.w * w3;
        }
        short8 v;
#pragma unroll
        for (int j = 0; j < 8; ++j)
            v[j] = (short)__bfloat16_as_ushort(
                __float2bfloat16(acc[j] * W2[(size_t)(j0 + j) * HH + k]));
        *(short8*)(Pp + ((size_t)tt * 64 + lane) * 8) = v;
    } else {
        float tv = t[0];
        b1eff[tid]       = b1[tid]       + tv * W1[(size_t)64 * HH + tid];
        b1eff[tid + 256] = b1[tid + 256] + tv * W1[(size_t)64 * HH + tid + 256];
    }
}

// ---------------------------------------------------------------------------
// mm_phase: one wave computes a [16 x 64] strip over K = NS*32.
// A: swizzled LDS (row stride RS elems), 1 ds_read_b128 per step.
// B: packed tiles from global; bb = pack + (first_tile*64 + lane)*8;
//    step s, sub-tile ni at bb + (s*NT + ni)*512. Depth-2 static ring
//    b[3][4] -- ALL indices compile-time; accs as scalar refs (no arrays
//    by pointer -> nothing can fall to scratch).
// ---------------------------------------------------------------------------
template <int NS, int NT, int RS>
__device__ __forceinline__ void mm_phase(
    const bf16* __restrict__ aT, int arow, int kq, int ckBase,
    const bf16* __restrict__ bb,
    f32x4& a0, f32x4& a1, f32x4& a2, f32x4& a3)
{
    const int rx = arow & 7;
    const bf16* pa = aT + arow * RS;
    short8 b[3][4];
#pragma unroll
    for (int ni = 0; ni < 4; ++ni)
        b[0][ni] = *(const short8*)(bb + ni * 512);
    if (NS > 1) {
#pragma unroll
        for (int ni = 0; ni < 4; ++ni)
            b[1][ni] = *(const short8*)(bb + (NT + ni) * 512);
    }
#pragma unroll
    for (int s = 0; s < NS; ++s) {
        short8 av = *(const short8*)(pa + (((ckBase + s * 4 + kq) ^ rx) << 3));
        if (s + 2 < NS) {
#pragma unroll
            for (int ni = 0; ni < 4; ++ni)
                b[(s + 2) % 3][ni] = *(const short8*)(bb + ((s + 2) * NT + ni) * 512);
        }
        a0 = __builtin_amdgcn_mfma_f32_16x16x32_bf16(av, b[s % 3][0], a0, 0, 0, 0);
        a1 = __builtin_amdgcn_mfma_f32_16x16x32_bf16(av, b[s % 3][1], a1, 0, 0, 0);
        a2 = __builtin_amdgcn_mfma_f32_16x16x32_bf16(av, b[s % 3][2], a2, 0, 0, 0);
        a3 = __builtin_amdgcn_mfma_f32_16x16x32_bf16(av, b[s % 3][3], a3, 0, 0, 0);
    }
}

// ---------------------------------------------------------------------------
// fused_rows: 256 blocks x 512 threads (8 waves). Block = 16 batch rows
// through L1 -> L2 -> E -> L3; h1/a/h2 in swizzled LDS; packed weights
// streamed from L2 (wave w owns cols [64w,64w+64) in N=512 phases).
// Trace: in-wave shfl reduce + LDS partials. L3: 8-way split-K + LDS
// reduce. No atomics, fully deterministic.
// ---------------------------------------------------------------------------
__global__ __launch_bounds__(512) void fused_rows(
    const float* __restrict__ z, const bf16* __restrict__ W1p,
    const bf16* __restrict__ W2p, const bf16* __restrict__ W3p,
    const bf16* __restrict__ Pp, const float* __restrict__ b1eff,
    const float* __restrict__ b2, const float* __restrict__ b3,
    float* __restrict__ outV, float* __restrict__ outTr)
{
    __shared__ alignas(16) char smem[51712];
    bf16* zt = (bf16*)smem;                   // [16][64]  swizzled
    bf16* h1 = (bf16*)(smem + 2048);          // [16][512] swizzled
    bf16* at = (bf16*)(smem + 18432);         // [16][512] swizzled
    bf16* h2 = (bf16*)(smem + 34816);         // [16][512] swizzled
    float* trp = (float*)(smem + 51200);      // [8][16]
    float* vp  = (float*)(smem + 2048);       // [8][16][64] overlays h1+at

    const int tid  = threadIdx.x;
    const int wid  = tid >> 6;
    const int lane = tid & 63;
    const int r    = lane & 15;
    const int kq   = lane >> 4;
    const int bm   = blockIdx.x * 16;

    // ---- stage z: 16x64 f32 -> bf16 swizzled LDS ----
    {
        int row = tid >> 5;
        int col = (tid * 2) & 63;
        float2 v = *(const float2*)(z + (size_t)(bm + row) * DD + col);
        st_swz(zt, row, col,     64, v.x);
        st_swz(zt, row, col + 1, 64, v.y);
    }
    __syncthreads();

    // ---- L1: h1 = tanh(z @ W1 + b1eff); a = 1 - h1^2 ----
    {
        f32x4 acc[4] = {};
        mm_phase<2, 32, 64>(zt, r, kq, 0, W1p + ((size_t)wid * 256 + lane) * 8,
                            acc[0], acc[1], acc[2], acc[3]);
#pragma unroll
        for (int ni = 0; ni < 4; ++ni) {
            int col = wid * 64 + ni * 16 + r;
            float bias = b1eff[col];
#pragma unroll
            for (int v = 0; v < 4; ++v) {
                int row = kq * 4 + v;
                float h = tanh_fast(acc[ni][v] + bias);
                st_swz(h1, row, col, 512, h);
                st_swz(at, row, col, 512, fmaf(-h, h, 1.0f));
            }
        }
    }
    __syncthreads();

    // ---- L2: h2 = tanh(h1 @ W2 + b2); bsq kept in registers ----
    f32x4 bsq[4];
    {
        f32x4 acc[4] = {};
        mm_phase<16, 32, 512>(h1, r, kq, 0, W2p + ((size_t)wid * 256 + lane) * 8,
                              acc[0], acc[1], acc[2], acc[3]);
#pragma unroll
        for (int ni = 0; ni < 4; ++ni) {
            int col = wid * 64 + ni * 16 + r;
            float bias = b2[col];
#pragma unroll
            for (int v = 0; v < 4; ++v) {
                int row = kq * 4 + v;
                float h = tanh_fast(acc[ni][v] + bias);
                st_swz(h2, row, col, 512, h);
                bsq[ni][v] = fmaf(-h, h, 1.0f);
            }
        }
    }
    __syncthreads();

    // ---- E: V = a @ P; trace partial = sum_col V*bsq ----
    {
        f32x4 acc[4] = {};
        mm_phase<16, 32, 512>(at, r, kq, 0, Pp + ((size_t)wid * 256 + lane) * 8,
                              acc[0], acc[1], acc[2], acc[3]);
#pragma unroll
        for (int v = 0; v < 4; ++v) {
            float p = acc[0][v] * bsq[0][v] + acc[1][v] * bsq[1][v]
                    + acc[2][v] * bsq[2][v] + acc[3][v] * bsq[3][v];
            p += __shfl_xor(p, 1);
            p += __shfl_xor(p, 2);
            p += __shfl_xor(p, 4);
            p += __shfl_xor(p, 8);
            if (r == 0) trp[wid * 16 + kq * 4 + v] = p;
        }
    }
    __syncthreads();   // all waves done with at/h1 -> vp overlay safe

    // ---- L3: v = h2 @ W3 + b3; 8-way split-K (wave w: k in [64w,64w+64)) ----
    {
        f32x4 acc[4] = {};
        mm_phase<2, 4, 512>(h2, r, kq, wid * 8,
                            W3p + ((size_t)wid * 512 + lane) * 8,
                            acc[0], acc[1], acc[2], acc[3]);
#pragma unroll
        for (int ni = 0; ni < 4; ++ni)
#pragma unroll
            for (int v = 0; v < 4; ++v) {
                int row = kq * 4 + v, col = ni * 16 + r;
                vp[wid * 1024 + row * 64 + col] = acc[ni][v];
            }
    }
    __syncthreads();

    // ---- reduce: v outputs (+bias) and trace ----
#pragma unroll
    for (int i0 = 0; i0 < 1024; i0 += 512) {
        int i = i0 + tid;
        int row = i >> 6, col = i & 63;
        float s = 0.f;
#pragma unroll
        for (int w = 0; w < 8; ++w) s += vp[w * 1024 + i];
        outV[(size_t)(bm + row) * DD + col] = s + b3[col];
    }
    if (tid < 16) {
        float s = 0.f;
#pragma unroll
        for (int w = 0; w < 8; ++w) s += trp[w * 16 + tid];
        outTr[bm + tid] = -s;
    }
}

extern "C" void kernel_launch(void* const* d_in, const int* in_sizes, int n_in,
                              void* d_out, int out_size, void* d_ws, size_t ws_size,
                              hipStream_t stream)
{
    const float* z  = (const float*)d_in[0];
    const float* t  = (const float*)d_in[2];
    const float* W1 = (const float*)d_in[3];
    const float* b1 = (const float*)d_in[4];
    const float* W2 = (const float*)d_in[5];
    const float* b2 = (const float*)d_in[6];
    const float* W3 = (const float*)d_in[7];
    const float* b3 = (const float*)d_in[8];
    float* out = (float*)d_out;                 // v [4096*64] then dlogp [4096]
    float* out_tr = out + (size_t)BB * DD;

    char* w = (char*)d_ws;
    auto alloc = [&](size_t bytes) {
        char* p = w;
        w += (bytes + 255) & ~(size_t)255;
        return p;
    };
    bf16* W1p   = (bf16*)alloc((size_t)64  * 512 * 2);   // 64 tiles
    bf16* W2p   = (bf16*)alloc((size_t)512 * 512 * 2);   // 512 tiles
    bf16* W3p   = (bf16*)alloc((size_t)64  * 512 * 2);   // 64 tiles
    bf16* Pp    = (bf16*)alloc((size_t)512 * 512 * 2);   // 512 tiles
    float* b1eff = (float*)alloc((size_t)HH * 4);

    prep_kernel<<<289, 256, 0, stream>>>(t, W1, b1, W2, W3,
                                         W1p, W2p, W3p, Pp, b1eff);
    fused_rows<<<BB / 16, 512, 0, stream>>>(z, W1p, W2p, W3p, Pp,
                                            b1eff, b2, b3, out, out_tr);
}

// Round 9
// 29.842 us; speedup vs baseline: 7.1316x; 1.4951x over previous
//
#include <hip/hip_runtime.h>
#include <hip/hip_bf16.h>

#define BB 4096   // batch
#define DD 64     // event dim
#define HH 512    // hidden

typedef short short8 __attribute__((ext_vector_type(8)));   // 8 bf16
typedef float f32x4  __attribute__((ext_vector_type(4)));
typedef __hip_bfloat16 bf16;

// async global->LDS DMA, 16B/lane: src is per-lane, dest wave-uniform
#define GLOAD_LDS16(gp, lp)                                                \
  __builtin_amdgcn_global_load_lds(                                        \
      (const __attribute__((address_space(1))) void*)(gp),                 \
      (__attribute__((address_space(3))) void*)(lp), 16, 0, 0)

// branchless fast tanh: 1 - 2/(1+e^{2x}); exact limits at +-inf
__device__ __forceinline__ float tanh_fast(float x) {
    float e = __expf(2.0f * x);
    return 1.0f - __fdividef(2.0f, 1.0f + e);
}

// swizzled LDS bf16 store: 8-elem chunk XOR'd with row&7 (write side)
__device__ __forceinline__ void st_swz(bf16* base, int row, int col, int rs, float v) {
    base[row * rs + ((((col >> 3) ^ (row & 7))) << 3) + (col & 7)] = __float2bfloat16(v);
}

// ===========================================================================
// Packed weights, strip/entry-major: a GEMM B-operand [N out-cols x K] is
// split into 16-col x 32-k tiles (1 lane = 8 bf16 = 16B: col=nt*16+r,
// k=kt*32+kq*8+j). Tiles are ordered so each wave's per-step entry (2 tiles
// = 2KB) is LINEAR in memory:  off_elems = tileIdx*512, tileIdx enumerated
// entry-major per strip.  One stage = 2 coalesced 1KB global_load_lds.
// ===========================================================================

// ---------------------------------------------------------------------------
// prep kernel: 289 blocks x 256 (4 waves; 1 tile per wave per block)
//  [0,160)  : pack W1p(64) W2p(512) W3p(64) tiles, dst linear = T*512
//  [160,288): compute + pack Pp (512 tiles)
//  288      : b1eff[j] = b1[j] + t*W1[64][j]
// ---------------------------------------------------------------------------
__global__ __launch_bounds__(256) void prep_kernel(
    const float* __restrict__ t, const float* __restrict__ W1,
    const float* __restrict__ b1, const float* __restrict__ W2,
    const float* __restrict__ W3,
    bf16* __restrict__ W1p, bf16* __restrict__ W2p, bf16* __restrict__ W3p,
    bf16* __restrict__ Pp, float* __restrict__ b1eff)
{
    const int tid  = threadIdx.x;
    const int bx   = blockIdx.x;
    const int lane = tid & 63;
    const int r    = lane & 15;
    const int kq   = lane >> 4;

    if (bx < 160) {
        int T = bx * 4 + (tid >> 6);
        const float* src;
        bf16* dst;
        int stride;
        if (T < 64) {            // W1p: strip sp=T>>2, s=(T>>1)&1, e=T&1
            int s = (T >> 1) & 1, nt = ((T >> 2) << 1) + (T & 1);
            src = W1 + (size_t)(s * 32 + kq * 8) * HH + nt * 16 + r;
            stride = HH;
            dst = W1p + (size_t)T * 512 + lane * 8;
        } else if (T < 576) {    // W2p: tt = sp*32 + s*2 + e
            int tt = T - 64;
            int s = (tt >> 1) & 15, nt = ((tt >> 5) << 1) + (tt & 1);
            src = W2 + (size_t)(s * 32 + kq * 8) * HH + nt * 16 + r;
            stride = HH;
            dst = W2p + (size_t)tt * 512 + lane * 8;
        } else {                 // W3p: tt = w*8 + e4*2 + f
            int tt = T - 576;
            int w = tt >> 3, e4 = (tt >> 1) & 3, f = tt & 1;
            int kt = 2 * w + (e4 >> 1), nt = (e4 & 1) * 2 + f;
            src = W3 + (size_t)(kt * 32 + kq * 8) * DD + nt * 16 + r;
            stride = DD;
            dst = W3p + (size_t)tt * 512 + lane * 8;
        }
        short8 v;
#pragma unroll
        for (int j = 0; j < 8; ++j)
            v[j] = (short)__bfloat16_as_ushort(__float2bfloat16(src[(size_t)j * stride]));
        *(short8*)dst = v;
    } else if (bx < 288) {
        // Pp tile pt = sp*32 + s*2 + e : out-col k = nt*16+r, reduce j = s*32+kq*8+jj
        int pt = (bx - 160) * 4 + (tid >> 6);
        int s = (pt >> 1) & 15, nt = ((pt >> 5) << 1) + (pt & 1);
        int k  = nt * 16 + r;
        int j0 = s * 32 + kq * 8;
        float acc[8] = {};
        const float* w3row = W3 + (size_t)k * DD;
        for (int d = 0; d < DD; ++d) {
            float w3 = w3row[d];
            const float4* w1p4 = (const float4*)(W1 + (size_t)d * HH + j0);
            float4 x = w1p4[0], y = w1p4[1];
            acc[0] += x.x * w3; acc[1] += x.y * w3;
            acc[2] += x.z * w3; acc[3] += x.w * w3;
            acc[4] += y.x * w3; acc[5] += y.y * w3;
            acc[6] += y.z * w3; acc[7] += y.w * w3;
        }
        short8 v;
#pragma unroll
        for (int j = 0; j < 8; ++j)
            v[j] = (short)__bfloat16_as_ushort(
                __float2bfloat16(acc[j] * W2[(size_t)(j0 + j) * HH + k]));
        *(short8*)(Pp + (size_t)pt * 512 + lane * 8) = v;
    } else {
        float tv = t[0];
        b1eff[tid]       = b1[tid]       + tv * W1[(size_t)64 * HH + tid];
        b1eff[tid + 256] = b1[tid + 256] + tv * W1[(size_t)64 * HH + tid + 256];
    }
}

// stage entry s (2 x 1KB DMA) into ring slot; lgkmcnt(0) guards slot reuse
#define STAGE2(Wb, s, slot)                                                  \
  do {                                                                       \
    asm volatile("s_waitcnt lgkmcnt(0)" ::: "memory");                       \
    GLOAD_LDS16((Wb) + (size_t)(s) * 1024 + laneE,       myring + (slot) * 1024);        \
    GLOAD_LDS16((Wb) + (size_t)(s) * 1024 + 512 + laneE, myring + (slot) * 1024 + 512);  \
  } while (0)

// ---------------------------------------------------------------------------
// fused_rows: 256 blocks x 1024 threads (16 waves, 4/SIMD). Block = 16
// batch rows through L1 -> L2 -> E -> L3. Weights stream via wave-private
// 3-slot LDS DMA rings (global_load_lds + counted per-wave vmcnt) -- NO
// barriers inside any K-loop; 4 block barriers total. bsq stays in regs
// (same wave handles matching L2/E column strips). Deterministic.
// ---------------------------------------------------------------------------
__global__ __launch_bounds__(1024) void fused_rows(
    const float* __restrict__ z, const bf16* __restrict__ W1p,
    const bf16* __restrict__ W2p, const bf16* __restrict__ W3p,
    const bf16* __restrict__ Pp, const float* __restrict__ b1eff,
    const float* __restrict__ b2, const float* __restrict__ b3,
    float* __restrict__ outV, float* __restrict__ outTr)
{
    __shared__ alignas(1024) char smem[150528];
    bf16* ring = (bf16*)smem;                 // 16 waves x 3072 elems (6KB)
    bf16* zt   = (bf16*)(smem + 98304);       // [16][64]  swizzled
    bf16* h1   = (bf16*)(smem + 100352);      // [16][512] swizzled
    bf16* at   = (bf16*)(smem + 116736);      // [16][512] swizzled
    bf16* h2   = (bf16*)(smem + 133120);      // [16][512] swizzled
    float* trp = (float*)(smem + 149504);     // [16][16]
    float* vp  = (float*)(smem + 49152);      // [8][16][64] overlays hi rings

    const int tid  = threadIdx.x;
    const int wid  = tid >> 6;                // 0..15
    const int lane = tid & 63;
    const int r    = lane & 15;
    const int kq   = lane >> 4;
    const int rx   = r & 7;
    const int laneE = lane * 8;               // elems (16B/lane)
    const int bm   = blockIdx.x * 16;
    bf16* myring = ring + wid * 3072;

    // ---- issue L1 weight DMA early (hides under z staging) ----
    const bf16* Wb1 = W1p + (size_t)wid * 2048;
    STAGE2(Wb1, 0, 0);
    STAGE2(Wb1, 1, 1);

    // ---- stage z: 16x64 f32 -> bf16 swizzled (1 elem/thread) ----
    {
        int row = tid >> 6, col = tid & 63;
        st_swz(zt, row, col, 64, z[(size_t)(bm + row) * DD + col]);
    }
    __syncthreads();

    // ---- L1: h1 = tanh(z @ W1 + b1eff); a = 1-h1^2.  strip=32 cols ----
    f32x4 a0 = {}, a1 = {};
    asm volatile("s_waitcnt vmcnt(0)" ::: "memory");
#pragma unroll
    for (int s = 0; s < 2; ++s) {
        short8 av = *(const short8*)(zt + r * 64 + (((s * 4 + kq) ^ rx) << 3));
        short8 b0 = *(const short8*)(myring + s * 1024 + laneE);
        short8 b1v = *(const short8*)(myring + s * 1024 + 512 + laneE);
        a0 = __builtin_amdgcn_mfma_f32_16x16x32_bf16(av, b0, a0, 0, 0, 0);
        a1 = __builtin_amdgcn_mfma_f32_16x16x32_bf16(av, b1v, a1, 0, 0, 0);
    }
#pragma unroll
    for (int ni = 0; ni < 2; ++ni) {
        int col = wid * 32 + ni * 16 + r;
        float bias = b1eff[col];
#pragma unroll
        for (int v = 0; v < 4; ++v) {
            int row = kq * 4 + v;
            float h = tanh_fast((ni ? a1[v] : a0[v]) + bias);
            st_swz(h1, row, col, 512, h);
            st_swz(at, row, col, 512, fmaf(-h, h, 1.0f));
        }
    }
    __syncthreads();

    // ---- L2: h2 = tanh(h1 @ W2 + b2); bsq kept in registers ----
    f32x4 bsq0, bsq1;
    {
        const bf16* Wb = W2p + (size_t)wid * 16384;
        f32x4 c0 = {}, c1 = {};
        STAGE2(Wb, 0, 0);
        STAGE2(Wb, 1, 1);
#pragma unroll
        for (int s = 0; s < 16; ++s) {
            if (s + 2 < 16) {
                STAGE2(Wb, s + 2, (s + 2) % 3);
                asm volatile("s_waitcnt vmcnt(4)" ::: "memory");
            } else if (s + 1 < 16) {
                asm volatile("s_waitcnt vmcnt(2)" ::: "memory");
            } else {
                asm volatile("s_waitcnt vmcnt(0)" ::: "memory");
            }
            const int slot = s % 3;
            short8 av = *(const short8*)(h1 + r * 512 + (((s * 4 + kq) ^ rx) << 3));
            short8 b0 = *(const short8*)(myring + slot * 1024 + laneE);
            short8 b1v = *(const short8*)(myring + slot * 1024 + 512 + laneE);
            c0 = __builtin_amdgcn_mfma_f32_16x16x32_bf16(av, b0, c0, 0, 0, 0);
            c1 = __builtin_amdgcn_mfma_f32_16x16x32_bf16(av, b1v, c1, 0, 0, 0);
        }
#pragma unroll
        for (int ni = 0; ni < 2; ++ni) {
            int col = wid * 32 + ni * 16 + r;
            float bias = b2[col];
#pragma unroll
            for (int v = 0; v < 4; ++v) {
                int row = kq * 4 + v;
                float h = tanh_fast((ni ? c1[v] : c0[v]) + bias);
                st_swz(h2, row, col, 512, h);
                if (ni) bsq1[v] = fmaf(-h, h, 1.0f);
                else    bsq0[v] = fmaf(-h, h, 1.0f);
            }
        }
    }

    // ---- E: V = a @ P (no barrier needed -- reads at, own ring) ----
    {
        const bf16* Wb = Pp + (size_t)wid * 16384;
        f32x4 c0 = {}, c1 = {};
        STAGE2(Wb, 0, 0);
        STAGE2(Wb, 1, 1);
#pragma unroll
        for (int s = 0; s < 16; ++s) {
            if (s + 2 < 16) {
                STAGE2(Wb, s + 2, (s + 2) % 3);
                asm volatile("s_waitcnt vmcnt(4)" ::: "memory");
            } else if (s + 1 < 16) {
                asm volatile("s_waitcnt vmcnt(2)" ::: "memory");
            } else {
                asm volatile("s_waitcnt vmcnt(0)" ::: "memory");
            }
            const int slot = s % 3;
            short8 av = *(const short8*)(at + r * 512 + (((s * 4 + kq) ^ rx) << 3));
            short8 b0 = *(const short8*)(myring + slot * 1024 + laneE);
            short8 b1v = *(const short8*)(myring + slot * 1024 + 512 + laneE);
            c0 = __builtin_amdgcn_mfma_f32_16x16x32_bf16(av, b0, c0, 0, 0, 0);
            c1 = __builtin_amdgcn_mfma_f32_16x16x32_bf16(av, b1v, c1, 0, 0, 0);
        }
        // trace partial: p(row) = sum over this wave's 32 cols of V*bsq
#pragma unroll
        for (int v = 0; v < 4; ++v) {
            float p = c0[v] * bsq0[v] + c1[v] * bsq1[v];
            p += __shfl_xor(p, 1);
            p += __shfl_xor(p, 2);
            p += __shfl_xor(p, 4);
            p += __shfl_xor(p, 8);
            if (r == 0) trp[wid * 16 + kq * 4 + v] = p;
        }
    }
    __syncthreads();   // h2 complete; all rings idle; trp written

    // ---- L3: v = h2 @ W3 + b3; waves 0-7, split-K (wave w: k in [64w,+64)) ----
    if (wid < 8) {
        const bf16* Wb3 = W3p + (size_t)wid * 4096;
        f32x4 c0 = {}, c1 = {}, c2 = {}, c3 = {};
        STAGE2(Wb3, 0, 0);
        STAGE2(Wb3, 1, 1);
        STAGE2(Wb3, 2, 2);
        // step 0: entries 0,1 (kt=2w, nt 0..3)
        asm volatile("s_waitcnt vmcnt(2)" ::: "memory");
        {
            short8 av = *(const short8*)(h2 + r * 512 + (((wid * 8 + kq) ^ rx) << 3));
            short8 b0 = *(const short8*)(myring + laneE);
            short8 b1v = *(const short8*)(myring + 512 + laneE);
            short8 b2v = *(const short8*)(myring + 1024 + laneE);
            short8 b3v = *(const short8*)(myring + 1536 + laneE);
            c0 = __builtin_amdgcn_mfma_f32_16x16x32_bf16(av, b0, c0, 0, 0, 0);
            c1 = __builtin_amdgcn_mfma_f32_16x16x32_bf16(av, b1v, c1, 0, 0, 0);
            c2 = __builtin_amdgcn_mfma_f32_16x16x32_bf16(av, b2v, c2, 0, 0, 0);
            c3 = __builtin_amdgcn_mfma_f32_16x16x32_bf16(av, b3v, c3, 0, 0, 0);
        }
        STAGE2(Wb3, 3, 0);
        // step 1: entries 2,3 (kt=2w+1) in slots 2,0
        asm volatile("s_waitcnt vmcnt(0)" ::: "memory");
        {
            short8 av = *(const short8*)(h2 + r * 512 + (((wid * 8 + 4 + kq) ^ rx) << 3));
            short8 b0 = *(const short8*)(myring + 2048 + laneE);
            short8 b1v = *(const short8*)(myring + 2560 + laneE);
            short8 b2v = *(const short8*)(myring + laneE);
            short8 b3v = *(const short8*)(myring + 512 + laneE);
            c0 = __builtin_amdgcn_mfma_f32_16x16x32_bf16(av, b0, c0, 0, 0, 0);
            c1 = __builtin_amdgcn_mfma_f32_16x16x32_bf16(av, b1v, c1, 0, 0, 0);
            c2 = __builtin_amdgcn_mfma_f32_16x16x32_bf16(av, b2v, c2, 0, 0, 0);
            c3 = __builtin_amdgcn_mfma_f32_16x16x32_bf16(av, b3v, c3, 0, 0, 0);
        }
        // write split-K partials (overlays hi-wave rings, dead in this phase)
#pragma unroll
        for (int v = 0; v < 4; ++v) {
            int row = kq * 4 + v;
            vp[wid * 1024 + row * 64 + 0 * 16 + r]  = c0[v];
            vp[wid * 1024 + row * 64 + 1 * 16 + r]  = c1[v];
            vp[wid * 1024 + row * 64 + 2 * 16 + r]  = c2[v];
            vp[wid * 1024 + row * 64 + 3 * 16 + r]  = c3[v];
        }
    }
    __syncthreads();

    // ---- final reduce: outV (+b3) and outTr ----
    {
        int row = tid >> 6, col = tid & 63;
        float s = 0.f;
#pragma unroll
        for (int w = 0; w < 8; ++w) s += vp[w * 1024 + tid];
        outV[(size_t)(bm + row) * DD + col] = s + b3[col];
    }
    if (tid < 16) {
        float s = 0.f;
#pragma unroll
        for (int w = 0; w < 16; ++w) s += trp[w * 16 + tid];
        outTr[bm + tid] = -s;
    }
}

extern "C" void kernel_launch(void* const* d_in, const int* in_sizes, int n_in,
                              void* d_out, int out_size, void* d_ws, size_t ws_size,
                              hipStream_t stream)
{
    const float* z  = (const float*)d_in[0];
    const float* t  = (const float*)d_in[2];
    const float* W1 = (const float*)d_in[3];
    const float* b1 = (const float*)d_in[4];
    const float* W2 = (const float*)d_in[5];
    const float* b2 = (const float*)d_in[6];
    const float* W3 = (const float*)d_in[7];
    const float* b3 = (const float*)d_in[8];
    float* out = (float*)d_out;                 // v [4096*64] then dlogp [4096]
    float* out_tr = out + (size_t)BB * DD;

    char* w = (char*)d_ws;
    auto alloc = [&](size_t bytes) {
        char* p = w;
        w += (bytes + 255) & ~(size_t)255;
        return p;
    };
    bf16* W1p   = (bf16*)alloc((size_t)64  * 512 * 2);
    bf16* W2p   = (bf16*)alloc((size_t)512 * 512 * 2);
    bf16* W3p   = (bf16*)alloc((size_t)64  * 512 * 2);
    bf16* Pp    = (bf16*)alloc((size_t)512 * 512 * 2);
    float* b1eff = (float*)alloc((size_t)HH * 4);

    prep_kernel<<<289, 256, 0, stream>>>(t, W1, b1, W2, W3,
                                         W1p, W2p, W3p, Pp, b1eff);
    fused_rows<<<BB / 16, 1024, 0, stream>>>(z, W1p, W2p, W3p, Pp,
                                             b1eff, b2, b3, out, out_tr);
}

// Round 10
// 27.049 us; speedup vs baseline: 7.8680x; 1.1033x over previous
//
#include <hip/hip_runtime.h>
#include <hip/hip_bf16.h>

#define BB 4096   // batch
#define DD 64     // event dim
#define HH 512    // hidden

typedef short short8 __attribute__((ext_vector_type(8)));   // 8 bf16
typedef float f32x4  __attribute__((ext_vector_type(4)));
typedef __hip_bfloat16 bf16;

// branchless fast tanh: 1 - 2/(1+e^{2x}); exact limits at +-inf
__device__ __forceinline__ float tanh_fast(float x) {
    float e = __expf(2.0f * x);
    return 1.0f - __fdividef(2.0f, 1.0f + e);
}

// swizzled LDS bf16 store: 8-elem chunk XOR'd with row&7 (write side)
__device__ __forceinline__ void st_swz(bf16* base, int row, int col, int rs, float v) {
    base[row * rs + ((((col >> 3) ^ (row & 7))) << 3) + (col & 7)] = __float2bfloat16(v);
}

// issue one 4KB entry (4 x 1KB coalesced) into ring slot via inline asm --
// compiler CANNOT sink these; values land in VGPRs, guarded by counted vmcnt.
#define GLD4(slot, addr)                                                      \
  asm volatile("global_load_dwordx4 %0, %4, off\n\t"                          \
               "global_load_dwordx4 %1, %4, off offset:1024\n\t"              \
               "global_load_dwordx4 %2, %4, off offset:2048\n\t"              \
               "global_load_dwordx4 %3, %4, off offset:3072"                  \
               : "=&v"(b[slot][0]), "=&v"(b[slot][1]),                        \
                 "=&v"(b[slot][2]), "=&v"(b[slot][3])                         \
               : "v"(addr))

// counted wait + compiler motion fence (rule 18)
#define WAITV(n)                                                              \
  do { asm volatile("s_waitcnt vmcnt(" #n ")" ::: "memory");                  \
       __builtin_amdgcn_sched_barrier(0); } while (0)

// ===========================================================================
// Packed weights: B-operand split into 16-col x 32-k tiles; lane l (kq=l>>4,
// r=l&15) owns B[col=nt*16+r][k=kt*32+kq*8+j], j=0..7 contiguous (16B).
// Tile linear order is (strip, step, frag): one wave-step entry = 4 frags =
// 4KB linear -> 4 coalesced 1KB loads at offsets 0/1024/2048/3072.
//   W1p: T = sp*8  + s*4 + f   (sp 0..7, s 0..1,  f 0..3)  col=(sp*4+f)*16+r
//   W2p: T = sp*64 + s*4 + f   (sp 0..7, s 0..15, f 0..3)  col=(sp*4+f)*16+r
//   Pp : same as W2p; out-col = original k, reduce dim = j
//   W3p: T = w*8   + s2*4 + f  (w 0..7,  s2 0..1, f 0..3)  col=f*16+r,
//        k = w*64 + s2*32 + kq*8 + j   (split-K per wave)
// ===========================================================================
__global__ __launch_bounds__(256) void prep_kernel(
    const float* __restrict__ t, const float* __restrict__ W1,
    const float* __restrict__ b1, const float* __restrict__ W2,
    const float* __restrict__ W3,
    bf16* __restrict__ W1p, bf16* __restrict__ W2p, bf16* __restrict__ W3p,
    bf16* __restrict__ Pp, float* __restrict__ b1eff)
{
    const int tid  = threadIdx.x;
    const int bx   = blockIdx.x;
    const int lane = tid & 63;
    const int r    = lane & 15;
    const int kq   = lane >> 4;

    if (bx < 160) {
        int T = bx * 4 + (tid >> 6);     // 0..639
        const float* src;
        bf16* dst;
        int stride;
        if (T < 64) {            // W1p
            int sp = T >> 3, s = (T >> 2) & 1, f = T & 3;
            int col = (sp * 4 + f) * 16 + r;
            int k   = s * 32 + kq * 8;
            src = W1 + (size_t)k * HH + col;
            stride = HH;
            dst = W1p + (size_t)T * 512 + lane * 8;
        } else if (T < 576) {    // W2p
            int tt = T - 64;
            int sp = tt >> 6, s = (tt >> 2) & 15, f = tt & 3;
            int col = (sp * 4 + f) * 16 + r;
            int k   = s * 32 + kq * 8;
            src = W2 + (size_t)k * HH + col;
            stride = HH;
            dst = W2p + (size_t)tt * 512 + lane * 8;
        } else {                 // W3p
            int tt = T - 576;
            int w = tt >> 3, s2 = (tt >> 2) & 1, f = tt & 3;
            int col = f * 16 + r;
            int k   = w * 64 + s2 * 32 + kq * 8;
            src = W3 + (size_t)k * DD + col;
            stride = DD;
            dst = W3p + (size_t)tt * 512 + lane * 8;
        }
        short8 v;
#pragma unroll
        for (int j = 0; j < 8; ++j)
            v[j] = (short)__bfloat16_as_ushort(__float2bfloat16(src[(size_t)j * stride]));
        *(short8*)dst = v;
    } else if (bx < 288) {
        // Pp tile pt: out-col k = (sp*4+f)*16+r, reduce j = s*32+kq*8+jj
        int pt = (bx - 160) * 4 + (tid >> 6);    // 0..511
        int sp = pt >> 6, s = (pt >> 2) & 15, f = pt & 3;
        int k  = (sp * 4 + f) * 16 + r;
        int j0 = s * 32 + kq * 8;
        float acc[8] = {};
        const float* w3row = W3 + (size_t)k * DD;
        for (int d = 0; d < DD; ++d) {
            float w3 = w3row[d];
            const float4* w1p4 = (const float4*)(W1 + (size_t)d * HH + j0);
            float4 x = w1p4[0], y = w1p4[1];
            acc[0] += x.x * w3; acc[1] += x.y * w3;
            acc[2] += x.z * w3; acc[3] += x.w * w3;
            acc[4] += y.x * w3; acc[5] += y.y * w3;
            acc[6] += y.z * w3; acc[7] += y.w * w3;
        }
        short8 v;
#pragma unroll
        for (int j = 0; j < 8; ++j)
            v[j] = (short)__bfloat16_as_ushort(
                __float2bfloat16(acc[j] * W2[(size_t)(j0 + j) * HH + k]));
        *(short8*)(Pp + (size_t)pt * 512 + lane * 8) = v;
    } else {
        float tv = t[0];
        b1eff[tid]       = b1[tid]       + tv * W1[(size_t)64 * HH + tid];
        b1eff[tid + 256] = b1[tid + 256] + tv * W1[(size_t)64 * HH + tid + 256];
    }
}

// ---------------------------------------------------------------------------
// fused_rows: 256 blocks x 512 threads (8 waves, launch_bounds(512,2) so the
// register ring is NOT squeezed out). Block = 16 batch rows through
// L1 -> L2 -> E -> L3. Wave w owns cols [64w,64w+64) (L1/L2/E) and K-range
// [64w,64w+64) for L3 split-K. B streams straight into VGPRs (asm ring,
// counted vmcnt, never 0 mid-loop). A from swizzled LDS. 4 block barriers.
// No atomics; deterministic.
// ---------------------------------------------------------------------------
__global__ __launch_bounds__(512, 2) void fused_rows(
    const float* __restrict__ z, const bf16* __restrict__ W1p,
    const bf16* __restrict__ W2p, const bf16* __restrict__ W3p,
    const bf16* __restrict__ Pp, const float* __restrict__ b1eff,
    const float* __restrict__ b2, const float* __restrict__ b3,
    float* __restrict__ outV, float* __restrict__ outTr)
{
    __shared__ alignas(16) char smem[51712];
    bf16* zt   = (bf16*)smem;                 // [16][64]  swizzled
    bf16* h1   = (bf16*)(smem + 2048);        // [16][512] swizzled
    bf16* at   = (bf16*)(smem + 18432);       // [16][512] swizzled
    bf16* h2   = (bf16*)(smem + 34816);       // [16][512] swizzled
    float* trp = (float*)(smem + 51200);      // [8][16]
    float* vp  = (float*)(smem + 2048);       // [8][16][64] overlays h1+at

    const int tid  = threadIdx.x;
    const int wid  = tid >> 6;                // 0..7
    const int lane = tid & 63;
    const int r    = lane & 15;
    const int kq   = lane >> 4;
    const int rx   = r & 7;
    const int laneE = lane * 8;               // elems (16B per lane)
    const int bm   = blockIdx.x * 16;

    short8 b[3][4];                           // asm-held prefetch ring

    // ---- stage z first (compiler's own loads+waits fully contained) ----
    {
        int row = tid >> 5, col = (tid * 2) & 63;
        float2 v = *(const float2*)(z + (size_t)(bm + row) * DD + col);
        st_swz(zt, row, col,     64, v.x);
        st_swz(zt, row, col + 1, 64, v.y);
    }
    // bias for L1 (load before issuing asm prefetch)
    float bias1[4];
#pragma unroll
    for (int f = 0; f < 4; ++f) bias1[f] = b1eff[wid * 64 + f * 16 + r];

    // ---- L1 prefetch (2 entries) ----
    const bf16* Wb1 = W1p + (size_t)wid * 4096 + laneE;
    GLD4(0, Wb1);
    GLD4(1, Wb1 + 2048);
    __syncthreads();

    // ---- L1: h1 = tanh(z @ W1 + b1eff); a = 1-h1^2 ----
    {
        f32x4 acc[4] = {};
        WAITV(4);
        {
            short8 av = *(const short8*)(zt + r * 64 + ((kq ^ rx) << 3));
#pragma unroll
            for (int f = 0; f < 4; ++f)
                acc[f] = __builtin_amdgcn_mfma_f32_16x16x32_bf16(av, b[0][f], acc[f], 0, 0, 0);
        }
        WAITV(0);
        {
            short8 av = *(const short8*)(zt + r * 64 + (((4 + kq) ^ rx) << 3));
#pragma unroll
            for (int f = 0; f < 4; ++f)
                acc[f] = __builtin_amdgcn_mfma_f32_16x16x32_bf16(av, b[1][f], acc[f], 0, 0, 0);
        }
        // issue L2 prefetch before the barrier (pure weight reads)
        const bf16* Wb2 = W2p + (size_t)wid * 32768 + laneE;
        GLD4(0, Wb2);
        GLD4(1, Wb2 + 2048);
#pragma unroll
        for (int f = 0; f < 4; ++f) {
            int col = wid * 64 + f * 16 + r;
#pragma unroll
            for (int v = 0; v < 4; ++v) {
                int row = kq * 4 + v;
                float h = tanh_fast(acc[f][v] + bias1[f]);
                st_swz(h1, row, col, 512, h);
                st_swz(at, row, col, 512, fmaf(-h, h, 1.0f));
            }
        }
    }
    __syncthreads();

    // ---- L2: h2 = tanh(h1 @ W2 + b2); bsq kept in registers ----
    f32x4 bsq[4];
    {
        const bf16* Wb2 = W2p + (size_t)wid * 32768 + laneE;
        f32x4 acc[4] = {};
#pragma unroll
        for (int s = 0; s < 16; ++s) {
            if (s + 2 < 16) { GLD4((s + 2) % 3, Wb2 + (s + 2) * 2048); WAITV(8); }
            else if (s + 1 < 16) { WAITV(4); }
            else { WAITV(0); }
            short8 av = *(const short8*)(h1 + r * 512 + ((((s * 4 + kq)) ^ rx) << 3));
#pragma unroll
            for (int f = 0; f < 4; ++f)
                acc[f] = __builtin_amdgcn_mfma_f32_16x16x32_bf16(av, b[s % 3][f], acc[f], 0, 0, 0);
        }
        // bias first, then E prefetch, then epilogue math (overlap)
        float bias2[4];
#pragma unroll
        for (int f = 0; f < 4; ++f) bias2[f] = b2[wid * 64 + f * 16 + r];
        const bf16* WbE = Pp + (size_t)wid * 32768 + laneE;
        GLD4(0, WbE);
        GLD4(1, WbE + 2048);
#pragma unroll
        for (int f = 0; f < 4; ++f) {
            int col = wid * 64 + f * 16 + r;
#pragma unroll
            for (int v = 0; v < 4; ++v) {
                int row = kq * 4 + v;
                float h = tanh_fast(acc[f][v] + bias2[f]);
                st_swz(h2, row, col, 512, h);
                bsq[f][v] = fmaf(-h, h, 1.0f);
            }
        }
    }

    // ---- E: V = a @ P; trace partial (no barrier: reads at + own regs) ----
    {
        const bf16* WbE = Pp + (size_t)wid * 32768 + laneE;
        f32x4 acc[4] = {};
#pragma unroll
        for (int s = 0; s < 16; ++s) {
            if (s + 2 < 16) { GLD4((s + 2) % 3, WbE + (s + 2) * 2048); WAITV(8); }
            else if (s + 1 < 16) { WAITV(4); }
            else { WAITV(0); }
            short8 av = *(const short8*)(at + r * 512 + ((((s * 4 + kq)) ^ rx) << 3));
#pragma unroll
            for (int f = 0; f < 4; ++f)
                acc[f] = __builtin_amdgcn_mfma_f32_16x16x32_bf16(av, b[s % 3][f], acc[f], 0, 0, 0);
        }
        // issue L3 prefetch (2 entries) before epilogue
        const bf16* Wb3 = W3p + (size_t)wid * 4096 + laneE;
        GLD4(0, Wb3);
        GLD4(1, Wb3 + 2048);
        // trace partial: p(row) = sum over this wave's 64 cols of V*bsq
#pragma unroll
        for (int v = 0; v < 4; ++v) {
            float p = acc[0][v] * bsq[0][v] + acc[1][v] * bsq[1][v]
                    + acc[2][v] * bsq[2][v] + acc[3][v] * bsq[3][v];
            p += __shfl_xor(p, 1);
            p += __shfl_xor(p, 2);
            p += __shfl_xor(p, 4);
            p += __shfl_xor(p, 8);
            if (r == 0) trp[wid * 16 + kq * 4 + v] = p;
        }
    }
    __syncthreads();   // h2 complete everywhere; trp written; at/h1 now dead

    // ---- L3: v = h2 @ W3 + b3; split-K (wave w: k in [64w,64w+64)) ----
    {
        f32x4 acc[4] = {};
        WAITV(4);
        {
            short8 av = *(const short8*)(h2 + r * 512 + ((((wid * 8 + kq)) ^ rx) << 3));
#pragma unroll
            for (int f = 0; f < 4; ++f)
                acc[f] = __builtin_amdgcn_mfma_f32_16x16x32_bf16(av, b[0][f], acc[f], 0, 0, 0);
        }
        WAITV(0);
        {
            short8 av = *(const short8*)(h2 + r * 512 + ((((wid * 8 + 4 + kq)) ^ rx) << 3));
#pragma unroll
            for (int f = 0; f < 4; ++f)
                acc[f] = __builtin_amdgcn_mfma_f32_16x16x32_bf16(av, b[1][f], acc[f], 0, 0, 0);
        }
#pragma unroll
        for (int f = 0; f < 4; ++f)
#pragma unroll
            for (int v = 0; v < 4; ++v) {
                int row = kq * 4 + v;
                vp[wid * 1024 + row * 64 + f * 16 + r] = acc[f][v];
            }
    }
    __syncthreads();

    // ---- final reduce: outV (+b3) and outTr ----
#pragma unroll
    for (int i0 = 0; i0 < 1024; i0 += 512) {
        int i = i0 + tid;
        int row = i >> 6, col = i & 63;
        float s = 0.f;
#pragma unroll
        for (int w = 0; w < 8; ++w) s += vp[w * 1024 + i];
        outV[(size_t)(bm + row) * DD + col] = s + b3[col];
    }
    if (tid < 16) {
        float s = 0.f;
#pragma unroll
        for (int w = 0; w < 8; ++w) s += trp[w * 16 + tid];
        outTr[bm + tid] = -s;
    }
}

extern "C" void kernel_launch(void* const* d_in, const int* in_sizes, int n_in,
                              void* d_out, int out_size, void* d_ws, size_t ws_size,
                              hipStream_t stream)
{
    const float* z  = (const float*)d_in[0];
    const float* t  = (const float*)d_in[2];
    const float* W1 = (const float*)d_in[3];
    const float* b1 = (const float*)d_in[4];
    const float* W2 = (const float*)d_in[5];
    const float* b2 = (const float*)d_in[6];
    const float* W3 = (const float*)d_in[7];
    const float* b3 = (const float*)d_in[8];
    float* out = (float*)d_out;                 // v [4096*64] then dlogp [4096]
    float* out_tr = out + (size_t)BB * DD;

    char* w = (char*)d_ws;
    auto alloc = [&](size_t bytes) {
        char* p = w;
        w += (bytes + 255) & ~(size_t)255;
        return p;
    };
    bf16* W1p   = (bf16*)alloc((size_t)64  * 512 * 2);
    bf16* W2p   = (bf16*)alloc((size_t)512 * 512 * 2);
    bf16* W3p   = (bf16*)alloc((size_t)64  * 512 * 2);
    bf16* Pp    = (bf16*)alloc((size_t)512 * 512 * 2);
    float* b1eff = (float*)alloc((size_t)HH * 4);

    prep_kernel<<<289, 256, 0, stream>>>(t, W1, b1, W2, W3,
                                         W1p, W2p, W3p, Pp, b1eff);
    fused_rows<<<BB / 16, 512, 0, stream>>>(z, W1p, W2p, W3p, Pp,
                                            b1eff, b2, b3, out, out_tr);
}